// Round 13
// baseline (608.102 us; speedup 1.0000x reference)
//
#include <hip/hip_runtime.h>

// Greedy NMS: keep[i] = !any(keep[j] for j in knn[i] if j < i)
//
// Round-13 = Round-12 (best: 598us) + three on-turn shaves:
//   - phase-1.5: ONE-SHOT pre-probe at pr >= b-1 (mirror + window-entry probes
//     vs all published chunks) while block b-1 computes; on-turn probes are
//     chunk b-1 only (lambda~0.9/row) and the final mirror is 64 words.
//     (R11 lesson respected: this is one extra wake, not per-tick work.)
//   - fixed-point convergence via __syncthreads_count (1 barrier/iter,
//     was 2-barrier chg flag), 2 monotone sweeps per iter.
//   - distance-scaled poll backoff (73 spinning wave-0s contend on one LLC
//     line; far blocks sleep long).
//
// Output encoding (validated round 4): INT32.
//   d_out[0..M)        : kept flags, 1 / 0
//   d_out[M..M+M*64)   : kept_knn, idx or 150000 (tail doubles as bitmask
//                        scratch, owned by block 73 which never publishes)
// d_ws[0..3]: progress counter (zeroed by init kernel each call)

#define M_ROWS 150000
#define KNN    64
#define BLK    1024
#define QRT    2
#define CHUNK  (BLK * QRT)                        // 2048
#define NCH    ((M_ROWS + CHUNK - 1) / CHUNK)     // 74
#define ICAP   6
#define ECAP   12
#define WCH    4                                  // exl window, chunks
#define LMW    (((NCH - 1) * CHUNK) / 32)         // 4672 u32 bitmask words
#define OUT_INTS (M_ROWS + M_ROWS * KNN)
#define BMG_OFF  (OUT_INTS - LMW)
#define SPINMAX  (1 << 22)

__global__ void init_ws_kernel(unsigned int* progress) {
  if (threadIdx.x == 0) *progress = 0u;
}

__device__ __forceinline__ unsigned int bm_load(const unsigned int* p) {
  return __hip_atomic_load(p, __ATOMIC_RELAXED, __HIP_MEMORY_SCOPE_AGENT);
}

// reload a row and probe preds j in [lo, hi) against the LDS bitmask
__device__ __forceinline__ bool probe_reload(const int* __restrict__ rp,
                                             const unsigned int* lm,
                                             int lo, int hi) {
  bool s = false;
#pragma unroll
  for (int u = 0; u < 16; ++u) {
    int4 d = ((const int4*)rp)[u];
    int js[4] = {d.x, d.y, d.z, d.w};
#pragma unroll
    for (int m = 0; m < 4; ++m) {
      int j = js[m];
      if (j >= lo && j < hi && ((lm[j >> 5] >> (j & 31)) & 1u)) s = true;
    }
  }
  return s;
}

__global__ __launch_bounds__(BLK) void nms_chain_kernel(
    const int* __restrict__ knn,
    int* __restrict__ out,
    unsigned int* __restrict__ progress)
{
  const int b    = blockIdx.x;
  const int t    = threadIdx.x;
  const int base = b * CHUNK;
  const int winb = (b > WCH) ? (base - WCH * CHUNK) : 0;   // exl window base

  unsigned int* bmg = (unsigned int*)out + BMG_OFF;
  unsigned long long* bmg64 = (unsigned long long*)bmg;

  __shared__ unsigned char      st[CHUNK];        // 0 unk, 1 kept, 2 supp
  __shared__ unsigned short     il[ICAP][CHUNK];  // transposed lists
  __shared__ unsigned short     exl[ECAP][CHUNK];
  __shared__ unsigned int       lm[LMW];          // mirrored keep bits
  __shared__ unsigned long long bw[QRT][BLK / 64];
  __shared__ unsigned int       sh_p;

  int  rowq[QRT];
  bool vq[QRT], ovf[QRT], eovf[QRT], supp[QRT];
  int  ic[QRT], ec[QRT];

#pragma unroll
  for (int q = 0; q < QRT; ++q) {
    rowq[q] = base + q * BLK + t;
    vq[q]   = rowq[q] < M_ROWS;
    ic[q] = ec[q] = 0;
    ovf[q] = eovf[q] = supp[q] = false;
  }

  // ---- classification: intra-chunk + static-window pred lists ----
#pragma unroll
  for (int q = 0; q < QRT; ++q) {
    if (!vq[q]) continue;
    const int o   = q * BLK + t;
    const int row = rowq[q];
    const int* rp = knn + (long long)row * KNN;
#pragma unroll
    for (int u = 0; u < 16; ++u) {
      int4 d = ((const int4*)rp)[u];
      int js[4] = {d.x, d.y, d.z, d.w};
#pragma unroll
      for (int m = 0; m < 4; ++m) {
        int j = js[m];
        if (j < row) {                            // strict <: ref semantics
          if (j >= base) {
            if (ic[q] < ICAP) il[ic[q]][o] = (unsigned short)(j - base);
            ++ic[q];
          } else if (j >= winb) {
            if (ec[q] < ECAP) exl[ec[q]][o] = (unsigned short)(j - winb);
            ++ec[q];
          }
          // j < winb: covered by the phase-1 reload probe
        }
      }
    }
  }
#pragma unroll
  for (int q = 0; q < QRT; ++q) {
    ovf[q]  = ic[q] > ICAP; if (ovf[q])  ic[q] = ICAP;
    eovf[q] = ec[q] > ECAP; if (eovf[q]) ec[q] = ECAP;
  }

  int probed_lim = 0;                             // preds j < probed_lim resolved
  int last_pr    = 0;                             // max progress observed
  int wcop       = 0;                             // lm words mirrored

  // ---- phase 1 (b > WCH): forced reload+probe ~WCH steps early ----
  if (b > WCH) {
    if (t < 64) {
      int pr = 0;
      for (int spin = 0; spin < SPINMAX; ++spin) {
        pr = (int)__hip_atomic_load(progress, __ATOMIC_RELAXED,
                                    __HIP_MEMORY_SCOPE_AGENT);
        if (pr >= b - WCH) break;
        if ((b - WCH) - pr > 8) __builtin_amdgcn_s_sleep(32);
        else                    __builtin_amdgcn_s_sleep(4);
      }
      if (t == 0) sh_p = (unsigned int)pr;
    }
    __syncthreads();                              // sh_p visible
    int praw1 = (int)sh_p; if (praw1 > b) praw1 = b;
    last_pr = praw1;
    const int wt = praw1 * (CHUNK / 32);
    for (int w = wcop + t; w < wt; w += BLK) lm[w] = bm_load(&bmg[w]);
    wcop = wt;
    __syncthreads();                              // lm visible
    const int lim = praw1 * CHUNK;
#pragma unroll
    for (int q = 0; q < QRT; ++q)
      if (vq[q] && !supp[q])
        supp[q] = probe_reload(knn + (long long)rowq[q] * KNN, lm, 0, lim);
    probed_lim = lim;
  }

  // ---- phase 1.5 (one-shot): pre-probe window entries at pr >= b-1 ----
  if (b >= 2 && last_pr < b - 1) {
    if (t < 64) {
      int pr = 0;
      for (int spin = 0; spin < SPINMAX; ++spin) {
        pr = (int)__hip_atomic_load(progress, __ATOMIC_RELAXED,
                                    __HIP_MEMORY_SCOPE_AGENT);
        if (pr >= b - 1) break;
        if ((b - 1) - pr > 8) __builtin_amdgcn_s_sleep(16);
        else                  __builtin_amdgcn_s_sleep(2);
      }
      if (t == 0) sh_p = (unsigned int)pr;
    }
    __syncthreads();                              // sh_p visible
    int praw2 = (int)sh_p; if (praw2 > b) praw2 = b;
    last_pr = praw2;
    const int wt = praw2 * (CHUNK / 32);
    for (int w = wcop + t; w < wt; w += BLK) lm[w] = bm_load(&bmg[w]);
    wcop = wt;
    __syncthreads();                              // lm visible
    const int lim2 = praw2 * CHUNK;
#pragma unroll
    for (int q = 0; q < QRT; ++q) {
      if (!vq[q] || supp[q]) continue;
      const int o = q * BLK + t;
      const int n = ec[q];
      for (int x = 0; x < n; ++x) {
        int j = winb + (int)exl[x][o];
        if (j >= probed_lim && j < lim2 &&
            ((lm[j >> 5] >> (j & 31)) & 1u)) { supp[q] = true; break; }
      }
    }
    probed_lim = lim2;
  }

  // ---- phase 2: wait for our turn ----
  if (b > 0 && last_pr < b) {
    if (t < 64) {
      for (int spin = 0; spin < SPINMAX; ++spin) {
        int pr = (int)__hip_atomic_load(progress, __ATOMIC_RELAXED,
                                        __HIP_MEMORY_SCOPE_AGENT);
        if (pr >= b) break;
        __builtin_amdgcn_s_sleep(1);
      }
    }
    __syncthreads();                              // turn detected
  }

  // ---- on-turn: final mirror (usually 64 words) + residual probes ----
  if (b > 0) {
    const int wt = b * (CHUNK / 32);
    for (int w = wcop + t; w < wt; w += BLK) lm[w] = bm_load(&bmg[w]);
    __syncthreads();                              // lm visible
#pragma unroll
    for (int q = 0; q < QRT; ++q) {
      if (!vq[q] || supp[q]) continue;
      const int o = q * BLK + t;
      const int n = ec[q];
      for (int x = 0; x < n; ++x) {
        int j = winb + (int)exl[x][o];
        if (j >= probed_lim && ((lm[j >> 5] >> (j & 31)) & 1u)) { supp[q] = true; break; }
      }
      if (!supp[q] && eovf[q])                    // dropped entries (rare)
        supp[q] = probe_reload(knn + (long long)rowq[q] * KNN, lm, winb, base);
    }
  }

  // ---- intra-chunk monotone fixed-point (count-based, 1 barrier/iter) ----
#pragma unroll
  for (int q = 0; q < QRT; ++q) {
    const int o = q * BLK + t;
    st[o] = (!vq[q] || supp[q]) ? (unsigned char)2
          : ((ic[q] == 0 && !ovf[q]) ? (unsigned char)1 : (unsigned char)0);
  }
  __syncthreads();

  for (int it = 0; it < CHUNK; ++it) {
    bool un = false;
#pragma unroll
    for (int s = 0; s < 2; ++s) {                 // monotone: stale reads safe
      un = false;
#pragma unroll
      for (int q = 0; q < QRT; ++q) {
        const int o = q * BLK + t;
        if (st[o] == 0) {
          bool anyK = false, allD = true;
          if (!ovf[q]) {
            for (int x = 0; x < ic[q]; ++x) {
              unsigned char v = st[il[x][o]];
              anyK |= (v == 1); allD &= (v != 0);
            }
          } else {                                // rare: rescan from global
            const int row = rowq[q];
            const int* rp = knn + (long long)row * KNN;
#pragma unroll
            for (int k = 0; k < KNN; ++k) {
              int j = rp[k];
              if (j >= base && j < row) {
                unsigned char v = st[j - base];
                anyK |= (v == 1); allD &= (v != 0);
              }
            }
          }
          if (anyK) st[o] = 2; else if (allD) st[o] = 1;
          if (st[o] == 0) un = true;
        }
      }
    }
    if (__syncthreads_count((int)un) == 0) break;
  }

  // ---- publish: ballots -> LDS -> wave 0 stores + release ----
  bool kq[QRT];
#pragma unroll
  for (int q = 0; q < QRT; ++q)
    kq[q] = vq[q] && (st[q * BLK + t] == 1);

#pragma unroll
  for (int q = 0; q < QRT; ++q) {
    unsigned long long ba = __ballot(kq[q]);      // rows base+q*1024+w*64+lane
    if ((t & 63) == 0) bw[q][t >> 6] = ba;
  }
  __syncthreads();
  if (b < NCH - 1 && t < CHUNK / 64) {            // wave 0: 32 u64 words
    __hip_atomic_store(&bmg64[b * (CHUNK / 64) + t], bw[t >> 4][t & 15],
                       __ATOMIC_RELAXED, __HIP_MEMORY_SCOPE_AGENT);
  }
  if (t == 0)                                     // same wave: stores precede release
    __hip_atomic_store(progress, (unsigned int)(b + 1),
                       __ATOMIC_RELEASE, __HIP_MEMORY_SCOPE_AGENT);

  // ---- outputs (off the chain; block 73's knn overwrites dead bitmask) ----
#pragma unroll
  for (int q = 0; q < QRT; ++q)
    if (vq[q]) out[rowq[q]] = kq[q] ? 1 : 0;

#pragma unroll
  for (int q = 0; q < QRT; ++q) {
    if (!vq[q]) continue;
    const int row = rowq[q];
    const int* rp = knn + (long long)row * KNN;
    int* orow = out + M_ROWS + (long long)row * KNN;
    const bool k = kq[q];
#pragma unroll
    for (int u = 0; u < 16; ++u) {
      int4 d = ((const int4*)rp)[u];
      int4 o4;
      o4.x = k ? d.x : M_ROWS;
      o4.y = k ? d.y : M_ROWS;
      o4.z = k ? d.z : M_ROWS;
      o4.w = k ? d.w : M_ROWS;
      ((int4*)orow)[u] = o4;
    }
  }
}

extern "C" void kernel_launch(void* const* d_in, const int* in_sizes, int n_in,
                              void* d_out, int out_size, void* d_ws, size_t ws_size,
                              hipStream_t stream) {
  const int* knn = (const int*)d_in[1];
  int* out = (int*)d_out;
  unsigned int* progress = (unsigned int*)d_ws;

  init_ws_kernel<<<1, 64, 0, stream>>>(progress);
  nms_chain_kernel<<<NCH, BLK, 0, stream>>>(knn, out, progress);
}